// Round 9
// baseline (407.996 us; speedup 1.0000x reference)
//
#include <hip/hip_runtime.h>
#include <hip/hip_bf16.h>

typedef unsigned int uint;
typedef unsigned short ushort;
typedef float v2f __attribute__((ext_vector_type(2)));
typedef uint v4u __attribute__((ext_vector_type(4)));   // clang vec for nt-store

#define NATOMS 20000
#define NEDGES 640000
#define FD 128
#define F3 384
#define NR 20
#define MAPB 16     // atoms per block, MLP
#define GAPB 2      // atoms per block, gather
#define CAPMAX 80   // bin capacity: mean degree 32, ~11 sigma headroom
#define CNTS 16     // cnt stride in ints: one 64B line per atom

__device__ __forceinline__ uint f2bfu(float f) {   // f32 -> bf16 bits, RNE
  const uint u = __float_as_uint(f);
  return (u + 0x7FFFu + ((u >> 16) & 1u)) >> 16;
}
__device__ __forceinline__ float bflo(uint u) { return __uint_as_float(u << 16); }
__device__ __forceinline__ float bfhi(uint u) { return __uint_as_float(u & 0xFFFF0000u); }

// ---------------------------------------------------------------------------
// Phase 1 (runs FIRST): x = silu(q@W1+b1)@W2+b2; pack per (atom,feature t) a
// 12B record [x0|x1, x2|m0, m1|m2] (bf16). Also zeroes padded cnt (no memset
// dispatch). K-loops quad-unrolled with float4 LDS broadcasts.
// UNCHANGED from R8.
// ---------------------------------------------------------------------------
__global__ __launch_bounds__(128) void mlp_kernel(
    const float* __restrict__ q, const float* __restrict__ mu,
    const float* __restrict__ W1, const float* __restrict__ b1,
    const float* __restrict__ W2, const float* __restrict__ b2v,
    uint* __restrict__ xmp, int* __restrict__ cnt)
{
  __shared__ float qL[MAPB][FD];
  __shared__ float hL[MAPB][FD];
  const int t = threadIdx.x;
  const int a0 = blockIdx.x * MAPB;

  // zero padded cnt: 1250 blocks x 256 ints = 320000 = NATOMS*CNTS
  cnt[blockIdx.x * 256 + t] = 0;
  cnt[blockIdx.x * 256 + 128 + t] = 0;

  #pragma unroll
  for (int a = 0; a < MAPB; ++a) qL[a][t] = q[(size_t)(a0 + a) * FD + t];
  __syncthreads();

  float hacc[MAPB];
  const float bb1 = b1[t];
  #pragma unroll
  for (int a = 0; a < MAPB; ++a) hacc[a] = bb1;
  for (int i = 0; i < FD; i += 4) {
    const float w0 = W1[(size_t)i * FD + t];
    const float w1 = W1[(size_t)(i + 1) * FD + t];
    const float w2 = W1[(size_t)(i + 2) * FD + t];
    const float w3 = W1[(size_t)(i + 3) * FD + t];
    #pragma unroll
    for (int a = 0; a < MAPB; ++a) {
      const float4 qv = *(const float4*)&qL[a][i];   // b128 broadcast
      hacc[a] += qv.x * w0 + qv.y * w1 + qv.z * w2 + qv.w * w3;
    }
  }
  #pragma unroll
  for (int a = 0; a < MAPB; ++a) hL[a][t] = hacc[a] / (1.f + __expf(-hacc[a]));
  __syncthreads();

  float x0[MAPB], x1[MAPB], x2[MAPB];
  const float c0 = b2v[t], c1 = b2v[FD + t], c2 = b2v[2 * FD + t];
  #pragma unroll
  for (int a = 0; a < MAPB; ++a) { x0[a] = c0; x1[a] = c1; x2[a] = c2; }
  for (int i = 0; i < FD; i += 4) {
    const float wa0 = W2[(size_t)i * F3 + t];
    const float wa1 = W2[(size_t)(i + 1) * F3 + t];
    const float wa2 = W2[(size_t)(i + 2) * F3 + t];
    const float wa3 = W2[(size_t)(i + 3) * F3 + t];
    const float wb0 = W2[(size_t)i * F3 + FD + t];
    const float wb1 = W2[(size_t)(i + 1) * F3 + FD + t];
    const float wb2 = W2[(size_t)(i + 2) * F3 + FD + t];
    const float wb3 = W2[(size_t)(i + 3) * F3 + FD + t];
    const float wc0 = W2[(size_t)i * F3 + 2 * FD + t];
    const float wc1 = W2[(size_t)(i + 1) * F3 + 2 * FD + t];
    const float wc2 = W2[(size_t)(i + 2) * F3 + 2 * FD + t];
    const float wc3 = W2[(size_t)(i + 3) * F3 + 2 * FD + t];
    #pragma unroll
    for (int a = 0; a < MAPB; ++a) {
      const float4 hv = *(const float4*)&hL[a][i];   // b128 broadcast
      x0[a] += hv.x * wa0 + hv.y * wa1 + hv.z * wa2 + hv.w * wa3;
      x1[a] += hv.x * wb0 + hv.y * wb1 + hv.z * wb2 + hv.w * wb3;
      x2[a] += hv.x * wc0 + hv.y * wc1 + hv.z * wc2 + hv.w * wc3;
    }
  }
  #pragma unroll
  for (int a = 0; a < MAPB; ++a) {
    const int n = a0 + a;
    const float* ma = mu + (size_t)n * F3;
    const float m0 = ma[t], m1 = ma[FD + t], m2 = ma[2 * FD + t];
    uint* dst = xmp + ((size_t)n * FD + t) * 3;
    dst[0] = f2bfu(x0[a]) | (f2bfu(x1[a]) << 16);
    dst[1] = f2bfu(x2[a]) | (f2bfu(m0) << 16);
    dst[2] = f2bfu(m1)    | (f2bfu(m2) << 16);
  }
}

// ---------------------------------------------------------------------------
// Prep: 16B record {ew0,ew1,ew2, j*1536} into atom i's fixed bin.
// UNCHANGED from R8.
// ---------------------------------------------------------------------------
__global__ __launch_bounds__(256) void prep_kernel(
    const int* __restrict__ eidx, const float* __restrict__ ew,
    int* __restrict__ cnt, uint* __restrict__ basisS, int cap)
{
  const int e = blockIdx.x * 256 + threadIdx.x;
  if (e >= NEDGES) return;
  const int i = eidx[e];
  const int j = eidx[NEDGES + e];
  const int pos = atomicAdd(&cnt[(size_t)i * CNTS], 1);
  if (pos >= cap) return;                    // runtime guard (never at cap=80)

  v4u r;
  r.x = __float_as_uint(ew[(size_t)e * 3 + 0]);
  r.y = __float_as_uint(ew[(size_t)e * 3 + 1]);
  r.z = __float_as_uint(ew[(size_t)e * 3 + 2]);
  r.w = (uint)j * (uint)(FD * 3 * 4);        // byte offset into xmp (j*1536)
  v4u* dst = (v4u*)(basisS + ((size_t)i * cap + pos) * 4);
  __builtin_nontemporal_store(r, dst);
}

// ---------------------------------------------------------------------------
// Phase 2 REWRITE: 64-thread blocks (ONE wave), GAPB=2 atoms.
// The 128-thread version was LDS-issue-bound: BOTH waves read the same 6
// b128 basis broadcasts per edge -> 2500 edges/CU x 12 reads x 12cyc ~ 150us
// (77% of its 197us). One wave per block reads the basis ONCE per edge;
// each thread owns SIX filter columns: features {t, 64+t} x groups {0,1,2}.
// Wf slice = 60 v2f = 120 VGPR -> __launch_bounds__(64,2) caps at 256 (no
// spill risk -- the R0/R6 failure mode). Two 12B gathers per edge per thread
// (features t and 64+t; two contiguous 768B segments per wave).
// Depth-2 prefetch, named scalars, branchless clamp.
// ---------------------------------------------------------------------------
__global__ __launch_bounds__(64, 2) void gather_kernel(
    const float* __restrict__ q, const float* __restrict__ mu,
    const uint* __restrict__ xmp,
    const float* __restrict__ Wf, const float* __restrict__ bfv,
    const int* __restrict__ cnt, const uint4* __restrict__ basisS,
    float* __restrict__ out, int cap)
{
  __shared__ float fb[64][28];     // [0..19] basis f32, [20..23] env+dir, [24] jbyte
  const int t = threadIdx.x;       // 0..63
  const int a0 = blockIdx.x * GAPB;
  const int tbA = t * 12;          // xmp byte offset, feature t
  const int tbB = (t + 64) * 12;   // xmp byte offset, feature 64+t
  const char* xmpC = (const char*)xmp;

  v2f wA0[10], wA1[10], wA2[10], wB0[10], wB1[10], wB2[10];
  #pragma unroll
  for (int r = 0; r < 10; ++r) {
    const float* w0p = Wf + (size_t)(2 * r) * F3;
    const float* w1p = Wf + (size_t)(2 * r + 1) * F3;
    wA0[r] = (v2f){w0p[t],        w1p[t]};
    wA1[r] = (v2f){w0p[128 + t],  w1p[128 + t]};
    wA2[r] = (v2f){w0p[256 + t],  w1p[256 + t]};
    wB0[r] = (v2f){w0p[64 + t],   w1p[64 + t]};
    wB1[r] = (v2f){w0p[192 + t],  w1p[192 + t]};
    wB2[r] = (v2f){w0p[320 + t],  w1p[320 + t]};
  }
  const float bA0 = bfv[t],      bA1 = bfv[128 + t], bA2 = bfv[256 + t];
  const float bB0 = bfv[64 + t], bB1 = bfv[192 + t], bB2 = bfv[320 + t];

  float qA = 0.f, m0A = 0.f, m1A = 0.f, m2A = 0.f;
  float qB = 0.f, m0B = 0.f, m1B = 0.f, m2B = 0.f;
  const size_t NQ = (size_t)NATOMS * FD;

  // per-edge compute: feature t (p*) and feature 64+t (r*)
  auto edge_compute = [&](int k, uint pX, uint pY, uint pZ,
                                 uint rX, uint rY, uint rZ) {
    const float* fk = fb[k];
    const float4 M = *(const float4*)(fk + 20);  // env, dir0..2 (b128 bcast)
    v2f sA0 = (v2f){0.f, 0.f}, sA1 = (v2f){0.f, 0.f}, sA2 = (v2f){0.f, 0.f};
    v2f sB0 = (v2f){0.f, 0.f}, sB1 = (v2f){0.f, 0.f}, sB2 = (v2f){0.f, 0.f};
    #pragma unroll
    for (int r4 = 0; r4 < 5; ++r4) {             // 5x ds_read_b128 broadcast
      const float4 bv = ((const float4*)fk)[r4];
      const v2f blo = (v2f){bv.x, bv.y};
      const v2f bhi = (v2f){bv.z, bv.w};
      sA0 += blo * wA0[2 * r4]; sA0 += bhi * wA0[2 * r4 + 1];
      sA1 += blo * wA1[2 * r4]; sA1 += bhi * wA1[2 * r4 + 1];
      sA2 += blo * wA2[2 * r4]; sA2 += bhi * wA2[2 * r4 + 1];
      sB0 += blo * wB0[2 * r4]; sB0 += bhi * wB0[2 * r4 + 1];
      sB1 += blo * wB1[2 * r4]; sB1 += bhi * wB1[2 * r4 + 1];
      sB2 += blo * wB2[2 * r4]; sB2 += bhi * wB2[2 * r4 + 1];
    }
    const float env = M.x;
    const float fA0 = sA0.x + sA0.y + env * bA0;
    const float fA1 = sA1.x + sA1.y + env * bA1;
    const float fA2 = sA2.x + sA2.y + env * bA2;
    const float fB0 = sB0.x + sB0.y + env * bB0;
    const float fB1 = sB1.x + sB1.y + env * bB1;
    const float fB2 = sB2.x + sB2.y + env * bB2;

    qA += fA0 * bflo(pX);
    const float dmuRA = fA1 * bfhi(pX);
    const float dmmA  = fA2 * bflo(pY);
    m0A += dmuRA * M.y + dmmA * bfhi(pY);
    m1A += dmuRA * M.z + dmmA * bflo(pZ);
    m2A += dmuRA * M.w + dmmA * bfhi(pZ);

    qB += fB0 * bflo(rX);
    const float dmuRB = fB1 * bfhi(rX);
    const float dmmB  = fB2 * bflo(rY);
    m0B += dmuRB * M.y + dmmB * bfhi(rY);
    m1B += dmuRB * M.z + dmmB * bflo(rZ);
    m2B += dmuRB * M.w + dmmB * bfhi(rZ);
  };

  for (int aa = 0; aa < GAPB; ++aa) {
    const int a = a0 + aa;
    int deg = cnt[(size_t)a * CNTS];
    if (deg > cap) deg = cap;                    // guard (never at cap=80)
    const uint4* bin = basisS + (size_t)a * cap;

    for (int cb = 0; cb < deg; cb += 64) {
      const int nn = min(64, deg - cb);
      __syncthreads();                           // fb reuse hazard
      if (t < nn) {
        const uint4 r = bin[cb + t];             // direct 16B coalesced load
        const float w0 = __uint_as_float(r.x);
        const float w1 = __uint_as_float(r.y);
        const float w2 = __uint_as_float(r.z);
        const float d = sqrtf(w0 * w0 + w1 * w1 + w2 * w2);
        const float invd = 1.f / d;
        float s1v, c1v;
        __sincosf(d * 0.628318530717958f, &s1v, &c1v);  // theta = pi*d/5
        const float env = (d < 5.f) ? 0.5f * (c1v + 1.f) : 0.f;
        fb[t][20] = env;
        fb[t][21] = w0 * invd;
        fb[t][22] = w1 * invd;
        fb[t][23] = w2 * invd;
        fb[t][24] = __uint_as_float(r.w);               // jbyte bits
        float vp = 0.f, vc = s1v * env * invd;
        const float tc2 = 2.f * c1v;
        #pragma unroll
        for (int r2 = 0; r2 < NR; ++r2) { fb[t][r2] = vc; const float vn = tc2 * vc - vp; vp = vc; vc = vn; }
      }
      __syncthreads();

      // prologue: fill both register sets (edges 0 and 1, clamped)
      uint aX, aY, aZ, aU, aV, aW, bX, bY, bZ, bU, bV, bW;
      {
        const uint j0 = __float_as_uint(fb[0][24]);
        const uint* xpA = (const uint*)(xmpC + j0 + tbA);
        const uint* xpB = (const uint*)(xmpC + j0 + tbB);
        aX = xpA[0]; aY = xpA[1]; aZ = xpA[2];
        aU = xpB[0]; aV = xpB[1]; aW = xpB[2];
        const int k1 = (nn > 1) ? 1 : 0;
        const uint j1 = __float_as_uint(fb[k1][24]);
        const uint* ypA = (const uint*)(xmpC + j1 + tbA);
        const uint* ypB = (const uint*)(xmpC + j1 + tbB);
        bX = ypA[0]; bY = ypA[1]; bZ = ypA[2];
        bU = ypB[0]; bV = ypB[1]; bW = ypB[2];
      }

      int k = 0;
      while (k < nn) {
        {                                        // edge k (set A)
          const uint cX = aX, cY = aY, cZ = aZ, cU = aU, cV = aV, cW = aW;
          const int kp = (k + 2 < nn) ? k + 2 : nn - 1;   // branchless clamp
          const uint jj = __float_as_uint(fb[kp][24]);
          const uint* xpA = (const uint*)(xmpC + jj + tbA);
          const uint* xpB = (const uint*)(xmpC + jj + tbB);
          aX = xpA[0]; aY = xpA[1]; aZ = xpA[2];
          aU = xpB[0]; aV = xpB[1]; aW = xpB[2];
          edge_compute(k, cX, cY, cZ, cU, cV, cW);
        }
        if (++k >= nn) break;
        {                                        // edge k (set B)
          const uint cX = bX, cY = bY, cZ = bZ, cU = bU, cV = bV, cW = bW;
          const int kp = (k + 2 < nn) ? k + 2 : nn - 1;
          const uint jj = __float_as_uint(fb[kp][24]);
          const uint* xpA = (const uint*)(xmpC + jj + tbA);
          const uint* xpB = (const uint*)(xmpC + jj + tbB);
          bX = xpA[0]; bY = xpA[1]; bZ = xpA[2];
          bU = xpB[0]; bV = xpB[1]; bW = xpB[2];
          edge_compute(k, cX, cY, cZ, cU, cV, cW);
        }
        ++k;
      }
    }

    // unconditional per-atom flush (handles deg==0 too); features t and 64+t
    out[(size_t)a * FD + t]      = q[(size_t)a * FD + t]      + qA;
    out[(size_t)a * FD + 64 + t] = q[(size_t)a * FD + 64 + t] + qB;
    const size_t mi = (size_t)a * F3;
    out[NQ + mi + t]        = mu[mi + t]        + m0A;
    out[NQ + mi + 64 + t]   = mu[mi + 64 + t]   + m0B;
    out[NQ + mi + 128 + t]  = mu[mi + 128 + t]  + m1A;
    out[NQ + mi + 192 + t]  = mu[mi + 192 + t]  + m1B;
    out[NQ + mi + 256 + t]  = mu[mi + 256 + t]  + m2A;
    out[NQ + mi + 320 + t]  = mu[mi + 320 + t]  + m2B;
    qA = m0A = m1A = m2A = 0.f;
    qB = m0B = m1B = m2B = 0.f;
  }
}

extern "C" void kernel_launch(void* const* d_in, const int* in_sizes, int n_in,
                              void* d_out, int out_size, void* d_ws, size_t ws_size,
                              hipStream_t stream) {
  const float* q   = (const float*)d_in[0];
  const float* mu  = (const float*)d_in[1];
  const int*   eix = (const int*)d_in[2];
  const float* ew  = (const float*)d_in[3];
  const float* W1  = (const float*)d_in[4];
  const float* b1  = (const float*)d_in[5];
  const float* W2  = (const float*)d_in[6];
  const float* b2v = (const float*)d_in[7];
  const float* Wf  = (const float*)d_in[8];
  const float* bfv = (const float*)d_in[9];
  float* out = (float*)d_out;

  // Workspace: [xmp 30.7MB | cnt(padded) 1.28MB | basisS 16B*N*cap (25.6MB @80)]
  char* w = (char*)d_ws;
  uint* xmp = (uint*)w;  w += (size_t)NATOMS * FD * 3 * sizeof(uint);
  int*  cnt = (int*)w;   w += (size_t)NATOMS * CNTS * sizeof(int);
  uint* basisS = (uint*)w;

  const size_t used = (size_t)NATOMS * FD * 3 * sizeof(uint)
                    + (size_t)NATOMS * CNTS * sizeof(int);
  int cap = CAPMAX;
  if (ws_size > used) {
    const size_t mx = (ws_size - used) / ((size_t)NATOMS * 16);
    if ((size_t)cap > mx) cap = (int)mx;       // degrade gracefully if ws tight
  }

  // mlp first (also zeroes cnt) -> prep -> gather. 3 dispatches, no memset.
  mlp_kernel<<<NATOMS / MAPB, 128, 0, stream>>>(q, mu, W1, b1, W2, b2v,
                                                xmp, cnt);

  prep_kernel<<<(NEDGES + 255) / 256, 256, 0, stream>>>(eix, ew, cnt,
                                                        basisS, cap);

  gather_kernel<<<NATOMS / GAPB, 64, 0, stream>>>(q, mu, xmp, Wf, bfv,
                                                  cnt, (const uint4*)basisS,
                                                  out, cap);
}